// Round 11
// baseline (136.732 us; speedup 1.0000x reference)
//
#include <hip/hip_runtime.h>
#include <hip/hip_fp16.h>

// DFMB PSROIAlign — row-line layout + channel-parallel lane remap.
//
// Ten-round model: main is pinned by L1 line-lookup throughput (~1 cycle per
// distinct 64B line per gather instruction). All prior schemes had 64 lanes
// on 64 distinct planes -> 64 lines/instr (37us floor). Sorting failed 4x on
// delivery cost; LDS-staged sharing failed on bank conflicts (R17); SW
// pipelining failed (R16/R18: compiler sinks loads, VGPR=64 proves it;
// and it's a throughput pin, not latency).
//
// R19: share lines WITHIN an instruction by remapping threads. Phase 2:
// wave = 4 rois x 16 lanes. R10 row-line layout packs a patch row (3 pixels
// x 10ch fp16 = 60B + 4B pad) into ONE 64B line; lane t of a group loads
// dword t of the group's row line -> 16 consecutive dwords = 1 line ->
// 4 distinct lines/instr (vs 64). 3 b32 gathers per (4-roi, bin) replace
// 12 b128 per roi: lookups/block 12288 -> 2352. Lane t owns channel-pair
// cp=t%5 of pixel q=t/5; accumulates rows p=0..2 in-register; __shfl reduce
// over q (t, t+5, t+10) -> lanes t<5 write the 10 channel sums to tile.
// Column clamp = clamped dword index min(q,e)*5+cp with RAW weights (exact
// R9 ftA semantics; only fp32 add order changes). Lane 15 reads the pad
// dword — prep zeroes it (NaN-safe).
//
// Row-line layout (R10, verified R10-R18): 3 phase copies of 64B lines;
// copy m line g = pixels [3g+m..3g+m+2]; window at pixel fp = one line
// (m=fp%3, g=fp/3). All lines fully written incl. 2 zero tail pixels.

#define NC 10
#define NBIN 49
#define FH 34
#define FW 34
#define PLANE (FH * FW)
#define NPIX (NBIN * PLANE)  // 56644
#define GPC 18882            // row-lines per phase copy
#define RPB 16               // rois per block
#define TSTRIDE 491          // out-tile row stride (odd -> conflict-free flush)
#define NSIDE 14

__device__ __forceinline__ void pack_pixel(
    const float* __restrict__ ft, unsigned int* __restrict__ ftR, int p)
{
    unsigned int h2[5];
    if (p < NPIX) {
#pragma unroll
        for (int c = 0; c < 5; ++c) {
            const __half lo = __float2half_rn(ft[(2 * c)     * NPIX + p]);
            const __half hi = __float2half_rn(ft[(2 * c + 1) * NPIX + p]);
            const __half2 hh = __halves2half2(lo, hi);
            h2[c] = *(const unsigned int*)&hh;
        }
    } else {
#pragma unroll
        for (int c = 0; c < 5; ++c) h2[c] = 0u;  // tail: finite zeros
    }
    // pixel p -> copy m (m<=p), line g=(p-m)/3, slot j=(p-m)%3
#pragma unroll
    for (int m = 0; m < 3; ++m) {
        if (p >= m) {
            const int t = p - m;
            const int g = t / 3;
            const int j = t - 3 * g;
            if (g < GPC) {
                unsigned int* d = ftR + ((size_t)m * GPC + g) * 16 + j * 5;
#pragma unroll
                for (int c = 0; c < 5; ++c) d[c] = h2[c];
                if (j == 0) d[15] = 0u;  // zero the pad dword (lane t=15 reads it)
            }
        }
    }
}

__global__ __launch_bounds__(1024) void prep_kernel(
    const float* __restrict__ ft, unsigned int* __restrict__ ftR)
{
    const int p = blockIdx.x * 1024 + threadIdx.x;
    if (p < NPIX + 2) pack_pixel(ft, ftR, p);
}

__device__ __forceinline__ void fma2(float w, unsigned int u, float& s0, float& s1)
{
    const __half2 h = *(const __half2*)&u;
    s0 = fmaf(w, __half2float(__low2half(h)),  s0);   // -> v_fma_mix_f32
    s1 = fmaf(w, __half2float(__high2half(h)), s1);
}

__global__ __launch_bounds__(256) void main_kernel(
    const float* __restrict__ rois, const unsigned int* __restrict__ ftR,
    const float* __restrict__ ft, float* __restrict__ out, int N, int use_t)
{
    __shared__ float sides[NSIDE][RPB][8];  // 7 KB
    __shared__ float tile[RPB][TSTRIDE];    // 31.4 KB

    const int r = threadIdx.x & (RPB - 1);  // roi within block (phase 1)
    const int s = threadIdx.x >> 4;         // slot 0..15 (phase 1)
    const int n = blockIdx.x * RPB + r;
    const bool valid = (n < N);

    float rsw = 0.f, rsh = 0.f, rew = 0.f, reh = 0.f;
    if (valid) {
        rsw = rois[n * 5 + 1] * 0.125f;  // /STRIDE(8), exact pow2
        rsh = rois[n * 5 + 2] * 0.125f;
        rew = rois[n * 5 + 3] * 0.125f;
        reh = rois[n * 5 + 4] * 0.125f;
    }
    // Explicit _rn chain: floor/ceil/compare inputs must bit-match numpy fp32.
    float rheight = __fsub_rn(reh, rsh);
    if (!(rheight > 0.1f)) rheight = 0.1f;
    float rwidth = __fsub_rn(rew, rsw);
    if (!(rwidth > 0.1f)) rwidth = 0.1f;
    const float bsh   = __fdiv_rn(rheight, 7.0f);
    const float bsw   = __fdiv_rn(rwidth, 7.0f);
    const float sub_h = __fdiv_rn(bsh, 4.0f);
    const float sub_w = __fdiv_rn(bsw, 4.0f);

    // ---- phase 1: one axis-side per slot (slots 0..13 active) ----
    if (s < NSIDE) {
        const bool isY = (s < 7);
        const int  k   = isY ? s : s - 7;
        const float st = isY ? rsh : rsw;
        const float bs = isY ? bsh : bsw;
        const float sb = isY ? sub_h : sub_w;
        const float start = floorf(__fadd_rn(st, __fmul_rn((float)k, bs)));

        float A[3] = {0.f, 0.f, 0.f}, B[3] = {0.f, 0.f, 0.f};
        float cnt = 0.f;
        int P0 = 0;
#pragma unroll
        for (int i = 0; i < 4; ++i) {
            const float h = __fadd_rn(start, __fmul_rn((float)i + 0.5f, sb));
            const bool ok = (h > -1.0f) && (h < 34.0f);
            const int p1 = (int)floorf(h);
            const int p2 = (int)ceilf(h);
            const bool v1 = (p1 >= 0) && (p1 < 34);
            const bool v2 = (p2 >= 0) && (p2 < 34);
            const int p1c = min(max(p1, 0), 33);
            const int p2c = min(max(p2, 0), 33);
            const float d = __fsub_rn(h, (float)p1c);  // vs CLIPPED corner
            if (i == 0) P0 = p1c;                      // min (h increasing)
            const int i1 = p1c - P0, i2 = p2c - P0;    // in {0,1,2}
            const float t1 = ok ? (1.0f - d) : 0.0f;
            const float t2 = ok ? d : 0.0f;
            // bad11 = (!x1v || !x2v) && (y1v || y2v): X carries "invalid",
            // Y carries "valid".
            const bool bsel = isY ? (v1 || v2) : ((!v1) || (!v2));
            const float tb = (ok && bsel) ? (1.0f - d) : 0.0f;
            cnt += ok ? 1.0f : 0.0f;
#pragma unroll
            for (int p = 0; p < 3; ++p) {
                A[p] += (i1 == p) ? t1 : 0.0f;
                A[p] += (i2 == p) ? t2 : 0.0f;
                B[p] += (i1 == p) ? tb : 0.0f;
            }
        }
        float* sp = &sides[s][r][0];
        sp[0] = A[0]; sp[1] = A[1]; sp[2] = A[2];
        sp[3] = B[0]; sp[4] = B[1]; sp[5] = B[2];
        sp[6] = cnt;  sp[7] = (float)P0;
    }
    __syncthreads();

    // ---- phase 2: channel-parallel remap; 3 b32 gathers per (4-roi, bin) ----
    if (use_t) {
        const int L   = threadIdx.x & 63;        // lane in wave
        const int wv  = threadIdx.x >> 6;        // wave 0..3
        const int grp = L >> 4;                  // roi-group within wave
        const int rr  = wv * 4 + grp;            // roi slot 0..15
        const int t   = L & 15;                  // dword slot within row line
        const int q   = t / 5;                   // pixel in row: 0,1,2 (3=pad lane)
        const int cp  = t - q * 5;               // channel pair 0..4
        const int n2  = blockIdx.x * RPB + rr;
        const bool vroi = (n2 < N);
        const float msk = (vroi && t != 15) ? 1.0f : 0.0f;

        for (int ph = 0; ph < 7; ++ph) {
            const float4 ya = *(const float4*)&sides[ph][rr][0];
            const float4 yb = *(const float4*)&sides[ph][rr][4];
            const int   Y0  = (int)yb.w;
            const int   yo0 = Y0 * FW;
            const int   yo1 = min(Y0 + 1, FH - 1) * FW;
            const int   yo2 = min(Y0 + 2, FH - 1) * FW;
            const float cy  = yb.z;

            for (int pw = 0; pw < 7; ++pw) {
                const int bin = ph * 7 + pw;
                const float4 xa = *(const float4*)&sides[7 + pw][rr][0];
                const float4 xb = *(const float4*)&sides[7 + pw][rr][4];
                const int X0 = (int)xb.w;
                const int e  = (FW - 1) - X0;          // clamp width
                const float cnt = cy * xb.z;
                const float inv = (cnt > 0.0f) ? __fdiv_rn(1.0f, cnt) : 1.0f;
                // per-lane X factors for its pixel q (raw weights,
                // clamped-index load = R9 ftA semantics)
                const float axq = (q == 0) ? xa.x : ((q == 1) ? xa.y : xa.z);
                const float bxq = (q == 0) ? xa.w : ((q == 1) ? xb.x : xb.y);
                const int   d   = min(q, e) * 5 + cp;  // clamped dword in line
                const int  base = bin * PLANE + X0;

                float s0 = 0.f, s1 = 0.f;
                {   // row p=0
                    const float w = (ya.x * axq - ya.w * bxq) * msk;
                    const int fp = vroi ? (base + yo0) : 0;
                    const int g = fp / 3;  const int m = fp - 3 * g;
                    fma2(w, ftR[((size_t)(m * GPC + g) << 4) + d], s0, s1);
                }
                {   // row p=1
                    const float w = (ya.y * axq - yb.x * bxq) * msk;
                    const int fp = vroi ? (base + yo1) : 0;
                    const int g = fp / 3;  const int m = fp - 3 * g;
                    fma2(w, ftR[((size_t)(m * GPC + g) << 4) + d], s0, s1);
                }
                {   // row p=2
                    const float w = (ya.z * axq - yb.y * bxq) * msk;
                    const int fp = vroi ? (base + yo2) : 0;
                    const int g = fp / 3;  const int m = fp - 3 * g;
                    fma2(w, ftR[((size_t)(m * GPC + g) << 4) + d], s0, s1);
                }
                // reduce over q: lanes t, t+5, t+10 -> lane t (t<5)
                const float r0 = s0 + __shfl(s0, (L + 5) & 63, 64)
                                    + __shfl(s0, (L + 10) & 63, 64);
                const float r1 = s1 + __shfl(s1, (L + 5) & 63, 64)
                                    + __shfl(s1, (L + 10) & 63, 64);
                if (vroi && t < 5) {
                    float* tp = &tile[rr][0];
                    tp[(2 * cp) * NBIN + bin]     = r0 * inv;
                    tp[(2 * cp + 1) * NBIN + bin] = r1 * inv;
                }
            }
        }
    } else {
        // fallback: direct fp32 gathers from ft (original mapping)
#pragma unroll
        for (int j = 0; j < 4; ++j) {
            const int bin = j * RPB + s;
            if (valid && bin < NBIN) {
                const int ph = bin / 7;
                const int pw = bin - ph * 7;
                const float4 ya = *(const float4*)&sides[ph][r][0];
                const float4 yb = *(const float4*)&sides[ph][r][4];
                const float4 xa = *(const float4*)&sides[7 + pw][r][0];
                const float4 xb = *(const float4*)&sides[7 + pw][r][4];
                const float AY[3] = {ya.x, ya.y, ya.z};
                const float BY[3] = {ya.w, yb.x, yb.y};
                const float AX[3] = {xa.x, xa.y, xa.z};
                const float BX[3] = {xa.w, xb.x, xb.y};
                const int Y0 = (int)yb.w, X0 = (int)xb.w;
                const float cnt = yb.z * xb.z;
                const int binbase = bin * PLANE;
                const int rowo[3] = {binbase + Y0 * FW,
                                     binbase + min(Y0 + 1, FH - 1) * FW,
                                     binbase + min(Y0 + 2, FH - 1) * FW};
                const int colo[3] = {X0, min(X0 + 1, FW - 1), min(X0 + 2, FW - 1)};
                float wgt[9];
                int off[9];
#pragma unroll
                for (int p = 0; p < 3; ++p)
#pragma unroll
                    for (int q2 = 0; q2 < 3; ++q2) {
                        const float w = AY[p] * AX[q2] - BY[p] * BX[q2];
                        wgt[3 * p + q2] = w;
                        off[3 * p + q2] = (w != 0.0f) ? (rowo[p] + colo[q2]) : binbase;
                    }
                float sum[NC];
#pragma unroll
                for (int c = 0; c < NC; ++c) sum[c] = 0.f;
#pragma unroll
                for (int k = 0; k < 9; ++k) {
                    const float w = wgt[k];
#pragma unroll
                    for (int c = 0; c < NC; ++c)
                        sum[c] = fmaf(w, ft[c * NPIX + off[k]], sum[c]);
                }
                const float inv = (cnt > 0.0f) ? __fdiv_rn(1.0f, cnt) : 1.0f;
                float* tp = &tile[r][0];
#pragma unroll
                for (int c = 0; c < NC; ++c) tp[c * NBIN + bin] = sum[c] * inv;
            }
        }
    }

    __syncthreads();

    // Coalesced flush: 16 rois x 490 contiguous floats each.
    const int n0 = blockIdx.x * RPB;
    for (int i = threadIdx.x; i < RPB * (NC * NBIN); i += 256) {
        const int row = i / (NC * NBIN);
        const int col = i - row * (NC * NBIN);
        const int n2 = n0 + row;
        if (n2 < N) out[(size_t)n2 * (NC * NBIN) + col] = tile[row][col];
    }
}

extern "C" void kernel_launch(void* const* d_in, const int* in_sizes, int n_in,
                              void* d_out, int out_size, void* d_ws, size_t ws_size,
                              hipStream_t stream) {
    const float* ft   = (const float*)d_in[0];
    const float* rois = (const float*)d_in[1];
    float* out        = (float*)d_out;
    const int N = in_sizes[1] / 5;

    // ws: ftR only (3 copies x GPC x 64B = 3,625,344 B)
    const size_t need = (size_t)3 * GPC * 64;
    const int use_t = (ws_size >= need) ? 1 : 0;
    unsigned int* ftR = (unsigned int*)d_ws;

    if (use_t) {
        prep_kernel<<<(NPIX + 2 + 1023) / 1024, 1024, 0, stream>>>(ft, ftR);
    }
    main_kernel<<<(N + RPB - 1) / RPB, 256, 0, stream>>>(rois, ftR, ft, out, N, use_t);
}